// Round 12
// baseline (352.325 us; speedup 1.0000x reference)
//
#include <hip/hip_runtime.h>
#include <cstdint>
#include <cstddef>

namespace {

typedef unsigned short ushort_t;
typedef _Float16 half_t;
typedef __attribute__((ext_vector_type(8))) short bf8v;     // 8 bf16
typedef __attribute__((ext_vector_type(8))) _Float16 h8v;   // 8 fp16
typedef __attribute__((ext_vector_type(4))) _Float16 h4v;   // 4 fp16
typedef __attribute__((ext_vector_type(4))) float f4v;      // MFMA acc

constexpr float BNS = 0.99999500003749973f; // 1/sqrt(1+1e-5)

constexpr int TB = 32;
constexpr int C  = 384;
constexpr int N  = 256;
constexpr int ROWS = 868;   // 96 k + 384 v + 4 router + 384 q
constexpr int HID = 2048;
constexpr int HH  = 1024;

// ---- workspace layout (float units) ----
constexpr size_t O_A1S  = 0;         // 896 (padded)
constexpr size_t O_A1B  = 896;
constexpr size_t O_APS  = 1792;
constexpr size_t O_APB  = 2176;
constexpr size_t O_AHS  = 2560;
constexpr size_t O_AHB  = 4608;
constexpr size_t O_ADS  = 6656;
constexpr size_t O_ADB  = 7680;
constexpr size_t O_AFS  = 8704;
constexpr size_t O_AFB  = 9088;
constexpr size_t O_DWT  = 9472;      // 9216 fp32 transposed dw weights
constexpr size_t O_WPRE0 = 18688;    // 896x384 half
constexpr size_t O_WPRE1 = 190720;
constexpr size_t O_WPRJ0 = 362752;   // 384x384
constexpr size_t O_WPRJ1 = 436480;
constexpr size_t O_WF10  = 510208;   // 2048x384
constexpr size_t O_WF11  = 903424;
constexpr size_t O_WF20  = 1296640;  // 384x1024
constexpr size_t O_WF21  = 1493248;
constexpr size_t O_XTPRE = 2023168;  // half x2 [32][256][384]
constexpr size_t O_SPKB  = 5168896;  // bf16 [32][868][256]
constexpr size_t O_QT    = 8724224;  // bf16 [128][256][96]
constexpr size_t O_KT    = 10297088; // bf16 [32][256][96]
constexpr size_t O_ATTNB = 10690304; // bf16 [128][256][256]
constexpr size_t O_YT    = 1689856;  // fp16 [32][256][384]
constexpr size_t O_XF0   = O_QT;     // fp16 [32][256][384] (QT dead after attn)
constexpr size_t O_XF1   = O_ATTNB;  // fp16 (ATTNB dead after res_y)
constexpr size_t O_H     = 14884608; // fp16 [32][256][2048]
constexpr size_t O_M     = 23273216; // fp16 [32][256][1024] -> ends 27467520

__device__ __forceinline__ void gload16(const void* g, void* l)
{
  __builtin_amdgcn_global_load_lds(
      (const __attribute__((address_space(1))) unsigned int*)g,
      (__attribute__((address_space(3))) unsigned int*)l, 16, 0, 0);
}

// ---------------- all affines + dw transpose in one launch ----------------
__global__ __launch_bounds__(256) void affines_all(
    const float* __restrict__ rb, const float* __restrict__ rg, const float* __restrict__ rbe,
    const float* __restrict__ eg, const float* __restrict__ eb,
    const float* __restrict__ pg, const float* __restrict__ pb, const float* __restrict__ pbe,
    const float* __restrict__ hg, const float* __restrict__ hb, const float* __restrict__ hbe,
    const float* __restrict__ dg, const float* __restrict__ db, const float* __restrict__ dbe,
    const float* __restrict__ fg, const float* __restrict__ fb, const float* __restrict__ fbe,
    const float* __restrict__ dw, float* __restrict__ ws)
{
  int u = blockIdx.x * 256 + threadIdx.x;
  if (u < 896) {
    float s, b;
    if (u < 480)      { s = 1.0f; b = 0.0f; }
    else if (u < 484) { int e = u - 480; s = rg[e] * BNS; b = rb[e] * rg[e] * BNS + rbe[e]; }
    else if (u < 868) { int j = u - 484; s = eg[j] * BNS; b = eb[j]; }
    else              { s = 0.0f; b = 0.0f; }
    ws[O_A1S + u] = s; ws[O_A1B + u] = b;
  } else if (u < 1280) {
    int j = u - 896;
    ws[O_APS + j] = pg[j] * BNS; ws[O_APB + j] = pb[j] * pg[j] * BNS + pbe[j];
  } else if (u < 3328) {
    int j = u - 1280;
    ws[O_AHS + j] = hg[j] * BNS; ws[O_AHB + j] = hb[j] * hg[j] * BNS + hbe[j];
  } else if (u < 4352) {
    int j = u - 3328;
    ws[O_ADS + j] = dg[j] * BNS; ws[O_ADB + j] = db[j] * dg[j] * BNS + dbe[j];
  } else if (u < 4736) {
    int j = u - 4352;
    ws[O_AFS + j] = fg[j] * BNS; ws[O_AFB + j] = fb[j] * fg[j] * BNS + fbe[j];
  } else if (u < 4736 + HH * 9) {
    int j = u - 4736; int ch = j / 9, i = j % 9;
    ws[O_DWT + i * HH + ch] = dw[j];
  }
}

// ---------------- all fp32 -> 2x fp16 weight splits in one launch ----------------
__global__ __launch_bounds__(256) void split_all(
    const float* __restrict__ kw, const float* __restrict__ vw,
    const float* __restrict__ rw, const float* __restrict__ ew,
    const float* __restrict__ pw, const float* __restrict__ f1w, const float* __restrict__ f2w,
    float* __restrict__ ws)
{
  int u = blockIdx.x * 256 + threadIdx.x;
  float v; size_t o0, o1; int idx;
  if (u < 344064) {
    int r = u / 384, d = u - r * 384;
    if (r < 96)       v = kw[r * 384 + d];
    else if (r < 480) v = vw[(r - 96) * 384 + d];
    else if (r < 484) v = rw[(r - 480) * 384 + d];
    else if (r < 868) v = ew[(r - 484) * 384 + d];
    else              v = 0.0f;
    o0 = O_WPRE0; o1 = O_WPRE1; idx = u;
  } else if (u < 491520) {
    idx = u - 344064; v = pw[idx]; o0 = O_WPRJ0; o1 = O_WPRJ1;
  } else if (u < 1277952) {
    idx = u - 491520; v = f1w[idx]; o0 = O_WF10; o1 = O_WF11;
  } else if (u < 1671168) {
    idx = u - 1277952; v = f2w[idx]; o0 = O_WF20; o1 = O_WF21;
  } else return;
  half_t h0 = (half_t)v;
  half_t h1 = (half_t)(v - (float)h0);
  ((half_t*)(ws + o0))[idx] = h0;
  ((half_t*)(ws + o1))[idx] = h1;
}

// ---------------- X [tb][D][N] fp32 -> XT0,XT1 [tb][N][D] fp16 (transpose + split) ----------
__global__ __launch_bounds__(256) void split_xt(
    const float* __restrict__ X, half_t* __restrict__ X0, half_t* __restrict__ X1, int D)
{
  __shared__ float tile[32][33];
  int tb = blockIdx.z, n0 = blockIdx.x * 32, d0 = blockIdx.y * 32;
  const float* src = X + (size_t)tb * D * N;
  int t = threadIdx.x;
  int nn = t & 31, ds = t >> 5;
#pragma unroll
  for (int l = 0; l < 4; ++l) {
    int dd = ds + 8 * l;
    tile[dd][nn] = src[(size_t)(d0 + dd) * N + n0 + nn];
  }
  __syncthreads();
  int dd2 = t & 31, ns = t >> 5;
#pragma unroll
  for (int l = 0; l < 4; ++l) {
    int nn2 = ns + 8 * l;
    float v = tile[dd2][nn2];
    half_t h0 = (half_t)v;
    half_t h1 = (half_t)(v - (float)h0);
    size_t o = ((size_t)tb * N + n0 + nn2) * D + d0 + dd2;
    X0[o] = h0; X1[o] = h1;
  }
}

// ======= LDS-staged split-fp16 MFMA GEMM + BN + LIF epilogue =======
// Tile: 32n x 64o x 4tt. BK=32. Double-buffered LDS via global_load_lds(16B).
// MODE 0 (PRE): spkb bf16 [tb][868][n]   MODE 1 (PROJ): out fp32 = xin + spike, + xf split
// MODE 2 (FC1): H fp16 NHWC [tb][n][O]   MODE 3 (FC2): out fp32 += spike
template<int NPROD, int MODE>
__global__ __launch_bounds__(256, 3) void sgemm_lif(
    const half_t* __restrict__ X0, const half_t* __restrict__ X1,
    const half_t* __restrict__ W0, const half_t* __restrict__ W1,
    const float* __restrict__ aS, const float* __restrict__ aB,
    const float* __restrict__ xin, void* __restrict__ dst,
    half_t* __restrict__ xo0, half_t* __restrict__ xo1,
    int O, int D)
{
  constexpr int XHALF = (NPROD == 3) ? 8192 : 4096;   // halves per X buffer
  __shared__ half_t smem[2 * (XHALF + 4096)];         // 48KB (NPROD3) / 32KB (NPROD2)
  half_t* xb0 = smem;
  half_t* xb1 = smem + XHALF;
  half_t* wb0 = smem + 2 * XHALF;
  half_t* wb1 = smem + 2 * XHALF + 4096;

  int b = blockIdx.z;
  int nblk = blockIdx.x * 32, o0 = blockIdx.y * 64;
  int tid = threadIdx.x, w = tid >> 6, l = tid & 63;
  int lr = l & 15, lk = l >> 4;
  int wn = w & 1, wo = w >> 1;

  auto STAGE = [&](int kt, int bi) {
    half_t* xb = bi ? xb1 : xb0;
    half_t* wb = bi ? wb1 : wb0;
    constexpr int XISS = (NPROD == 3) ? 4 : 2;
#pragma unroll
    for (int j = 0; j < XISS; ++j) {
      int gi = w * (XISS * 64) + j * 64 + l;
      int s = gi & 7, n = (gi >> 3) & 31, tz = gi >> 8;
      int g = s ^ (n & 7);
      int lk2 = g & 3;
      const half_t* src; int tt;
      if (NPROD == 3) { tt = tz; src = (g >> 2) ? X1 : X0; }
      else            { tt = tz * 2 + (g >> 2); src = X0; }
      const half_t* gp = src + ((size_t)((tt * 8 + b) * 256 + nblk + n)) * D + kt + lk2 * 8;
      gload16(gp, xb + (size_t)(w * (XISS * 64) + j * 64) * 8);
    }
#pragma unroll
    for (int j = 0; j < 2; ++j) {
      int gi = w * 128 + j * 64 + l;
      int s = gi & 7, ol = gi >> 3;
      int g = s ^ (ol & 7);
      const half_t* src = (g >> 2) ? W1 : W0;
      const half_t* gp = src + (size_t)(o0 + ol) * D + kt + (g & 3) * 8;
      gload16(gp, wb + (size_t)(w * 128 + j * 64) * 8);
    }
  };

  f4v acc[4][2] = {};   // [tt][ct]
  STAGE(0, 0);
  __syncthreads();
  int buf = 0;
  for (int kt = 0; kt < D; kt += 32) {
    if (kt + 32 < D) STAGE(kt + 32, buf ^ 1);
    half_t* xb = buf ? xb1 : xb0;
    half_t* wb = buf ? wb1 : wb0;
    h8v bb[2][2];
#pragma unroll
    for (int ct = 0; ct < 2; ++ct)
#pragma unroll
      for (int op = 0; op < 2; ++op) {
        int ol = wo * 32 + ct * 16 + lr;
        bb[ct][op] = *(const h8v*)(wb + ol * 64 + (((op << 2) | lk) ^ (ol & 7)) * 8);
      }
    h8v a[4][2];
    int nl = wn * 16 + lr;
#pragma unroll
    for (int tt = 0; tt < 4; ++tt)
#pragma unroll
      for (int op = 0; op < (NPROD == 3 ? 2 : 1); ++op) {
        int row = (NPROD == 3) ? (tt * 32 + nl) : ((tt >> 1) * 32 + nl);
        int g = (NPROD == 3) ? ((op << 2) | lk) : (((tt & 1) << 2) | lk);
        a[tt][op] = *(const h8v*)(xb + row * 64 + (g ^ (nl & 7)) * 8);
      }
#pragma unroll
    for (int tt = 0; tt < 4; ++tt)
#pragma unroll
      for (int ct = 0; ct < 2; ++ct) {
        acc[tt][ct] = __builtin_amdgcn_mfma_f32_16x16x32_f16(a[tt][0], bb[ct][0], acc[tt][ct], 0, 0, 0);
        acc[tt][ct] = __builtin_amdgcn_mfma_f32_16x16x32_f16(a[tt][0], bb[ct][1], acc[tt][ct], 0, 0, 0);
        if (NPROD == 3)
          acc[tt][ct] = __builtin_amdgcn_mfma_f32_16x16x32_f16(a[tt][1], bb[ct][0], acc[tt][ct], 0, 0, 0);
      }
    __syncthreads();
    buf ^= 1;
  }

  // BN + LIF (4 time steps in-register) -> spike bits (bit r*4+tt)
  unsigned sb_[2];
#pragma unroll
  for (int ct = 0; ct < 2; ++ct) {
    int o = o0 + wo * 32 + ct * 16 + lr;
    float s = aS[o], bbv = aB[o];
    unsigned bits = 0;
#pragma unroll
    for (int r = 0; r < 4; ++r) {
      float mem = 0.0f;
#pragma unroll
      for (int tt = 0; tt < 4; ++tt) {
        float z = acc[tt][ct][r] * s + bbv;
        mem += (z - mem) * 0.5f;
        if (mem >= 1.0f) { bits |= 1u << (r * 4 + tt); mem = 0.0f; }
      }
    }
    sb_[ct] = bits;
  }

  // LDS bounce + coalesced store, one pass per time step (smem reused)
  ushort_t* lsu = (ushort_t*)smem;   // MODE0: [64][40]; MODE2: [32][80]
  float*    lsf = (float*)smem;      // MODE1/3: [64][40]
  float*    lsx = (float*)smem + 64 * 40;  // MODE1: [32n][68] transposed sum
  for (int tt = 0; tt < 4; ++tt) {
    __syncthreads();
#pragma unroll
    for (int ct = 0; ct < 2; ++ct) {
      int ol = wo * 32 + ct * 16 + lr;
#pragma unroll
      for (int r = 0; r < 4; ++r) {
        int nl2 = wn * 16 + lk * 4 + r;
        bool fire = (sb_[ct] >> (r * 4 + tt)) & 1;
        if (MODE == 0)      lsu[ol * 40 + nl2] = fire ? (ushort_t)0x3F80 : (ushort_t)0;
        else if (MODE == 2) lsu[nl2 * 80 + ol] = fire ? (ushort_t)0x3C00 : (ushort_t)0;
        else                lsf[ol * 40 + nl2] = fire ? 1.0f : 0.0f;
      }
    }
    __syncthreads();
    int tb = tt * 8 + b;
    if (MODE == 0) {
      int row = tid >> 2, cb = (tid & 3) * 8;
      if (o0 + row < O) {
        ushort_t* dp = (ushort_t*)dst + ((size_t)tb * 868 + o0 + row) * 256 + nblk + cb;
        *(uint4*)dp = *(uint4*)&lsu[row * 40 + cb];
      }
    } else if (MODE == 2) {
      int row = tid >> 3, cb = (tid & 7) * 8;
      half_t* dp = (half_t*)dst + ((size_t)tb * 256 + nblk + row) * (size_t)O + o0 + cb;
      *(uint4*)dp = *(uint4*)&lsu[row * 80 + cb];
    } else if (MODE == 1) {
      int row = tid >> 2, cb = (tid & 3) * 8;
      float* op = (float*)dst + ((size_t)tb * O + o0 + row) * 256 + nblk + cb;
      const float* xp = xin + ((size_t)tb * O + o0 + row) * 256 + nblk + cb;
#pragma unroll
      for (int j = 0; j < 2; ++j) {
        float4 sv = *(float4*)&lsf[row * 40 + cb + j * 4];
        float4 xv = *(const float4*)(xp + j * 4);
        float4 ov = {xv.x + sv.x, xv.y + sv.y, xv.z + sv.z, xv.w + sv.w};
        *(float4*)(op + j * 4) = ov;
        lsx[(cb + j * 4 + 0) * 68 + row] = ov.x;
        lsx[(cb + j * 4 + 1) * 68 + row] = ov.y;
        lsx[(cb + j * 4 + 2) * 68 + row] = ov.z;
        lsx[(cb + j * 4 + 3) * 68 + row] = ov.w;
      }
      __syncthreads();
      // split-write xf: [tb][n][384] K-major halves
      int rn = tid >> 3, co = (tid & 7) * 8;
      h8v h0, h1;
#pragma unroll
      for (int j = 0; j < 8; ++j) {
        float v = lsx[rn * 68 + co + j];
        half_t a0 = (half_t)v;
        h0[j] = a0;
        h1[j] = (half_t)(v - (float)a0);
      }
      size_t xo = ((size_t)tb * 256 + nblk + rn) * 384 + o0 + co;
      *(h8v*)(xo0 + xo) = h0;
      *(h8v*)(xo1 + xo) = h1;
    } else {
      int row = tid >> 2, cb = (tid & 3) * 8;
      float* op = (float*)dst + ((size_t)tb * O + o0 + row) * 256 + nblk + cb;
#pragma unroll
      for (int j = 0; j < 2; ++j) {
        float4 sv = *(float4*)&lsf[row * 40 + cb + j * 4];
        float4 ov = *(float4*)(op + j * 4);
        ov.x += sv.x; ov.y += sv.y; ov.z += sv.z; ov.w += sv.w;
        *(float4*)(op + j * 4) = ov;
      }
    }
  }
}

// ---------------- transpose spikes: SPKB[tb][base+ey*96+c][n] -> dst[ey*32+tb][n][c] --------
__global__ __launch_bounds__(256) void transpose_spk(
    const ushort_t* __restrict__ SPKB, ushort_t* __restrict__ dst, int srcBase)
{
  __shared__ ushort_t tile[32][33];
  int z = blockIdx.z, tb = z & 31, ey = z >> 5;
  const ushort_t* src = SPKB + ((size_t)tb * ROWS + srcBase + ey * 96) * N;
  ushort_t* d = dst + (size_t)z * N * 96;
  int n0 = blockIdx.x * 32, c0 = blockIdx.y * 32;
  int t = threadIdx.x, nn = t & 31, cs = t >> 5;
#pragma unroll
  for (int l = 0; l < 4; ++l) {
    int cc = cs + 8 * l;
    tile[cc][nn] = src[(size_t)(c0 + cc) * N + n0 + nn];
  }
  __syncthreads();
  int cc2 = t & 31, ns = t >> 5;
#pragma unroll
  for (int l = 0; l < 4; ++l) {
    int nn2 = ns + 8 * l;
    d[(size_t)(n0 + nn2) * 96 + c0 + cc2] = tile[cc2][nn2];
  }
}

// ---------------- attn[bi][n][m] = sum_c QT[bi][n][c]*KT[tb][m][c] (bf16 MFMA, exact) -------
__global__ __launch_bounds__(256) void attn_mfma(
    const ushort_t* __restrict__ QT, const ushort_t* __restrict__ KT, ushort_t* __restrict__ ATTNB)
{
  int bi = blockIdx.y, tb = bi & 31;
  const ushort_t* q  = QT + (size_t)bi * N * 96;
  const ushort_t* kk = KT + (size_t)tb * N * 96;
  ushort_t* ob = ATTNB + (size_t)bi * N * N;
  int m0 = blockIdx.x * 128;
  int t = threadIdx.x, w = t >> 6, l = t & 63;
  int lr = l & 15, lk = l >> 4;
  int nb = w * 64;
  f4v acc[4][8] = {};
  for (int kt = 0; kt < 96; kt += 32) {
    bf8v a[4], b[8];
#pragma unroll
    for (int rt = 0; rt < 4; ++rt)
      a[rt] = *reinterpret_cast<const bf8v*>(q + (size_t)(nb + rt * 16 + lr) * 96 + kt + lk * 8);
#pragma unroll
    for (int ct = 0; ct < 8; ++ct)
      b[ct] = *reinterpret_cast<const bf8v*>(kk + (size_t)(m0 + ct * 16 + lr) * 96 + kt + lk * 8);
#pragma unroll
    for (int rt = 0; rt < 4; ++rt)
#pragma unroll
      for (int ct = 0; ct < 8; ++ct)
        acc[rt][ct] = __builtin_amdgcn_mfma_f32_16x16x32_bf16(a[rt], b[ct], acc[rt][ct], 0, 0, 0);
  }
#pragma unroll
  for (int rt = 0; rt < 4; ++rt)
#pragma unroll
    for (int ct = 0; ct < 8; ++ct)
#pragma unroll
      for (int r = 0; r < 4; ++r) {
        int n = nb + rt * 16 + lk * 4 + r;
        int m = m0 + ct * 16 + lr;
        float v = acc[rt][ct][r];
        ob[(size_t)n * N + m] = (ushort_t)(__builtin_bit_cast(unsigned, v) >> 16);
      }
}

// ======= fused res GEMM + RES-LIF + router-weighted expert sum -> YT fp16 =======
// Flat grid 768, XCD-locality decode: b = bid&7 (XCD i owns batch i -> per-XCD
// working set A(.,b)=2.1MB + V(.,b)=0.8MB fits the 4MB private L2).
// res[e,t][n][d] = sum_m ATTNB[e*32+t*8+b][n][m] * v_spk[t*8+b][d][m]  (exact ints)
__global__ __launch_bounds__(256) void res_y(
    const ushort_t* __restrict__ ATTNB, const ushort_t* __restrict__ SPKB,
    half_t* __restrict__ YT)
{
  __shared__ ushort_t wlds[512];      // [e][t][32n] router spikes
  __shared__ half_t wt[4][32][36];    // per-expert contribution tile
  int bid = blockIdx.x;
  int b = bid & 7;
  int r9 = bid >> 3;               // 0..95
  int n0 = (r9 & 7) * 32;
  int d0 = (r9 >> 3) * 32;
  int tid = threadIdx.x, e = tid >> 6, l = tid & 63;
  int lr = l & 15, lk = l >> 4;
  for (int j = tid; j < 512; j += 256) {
    int ee = j >> 7, t = (j >> 5) & 3, nl = j & 31;
    wlds[j] = SPKB[((size_t)((t * 8 + b) * ROWS) + 480 + ee) * 256 + n0 + nl];
  }
  __syncthreads();
  f4v acc[4][2][2] = {};   // [t][rt][ct]
#pragma unroll
  for (int t = 0; t < 4; ++t) {
    const ushort_t* A = ATTNB + (size_t)(e * 32 + t * 8 + b) * 65536;
    const ushort_t* V = SPKB + ((size_t)((t * 8 + b) * ROWS) + 96) * 256;
#pragma unroll
    for (int kt = 0; kt < 256; kt += 32) {
      bf8v a[2], bb[2];
#pragma unroll
      for (int rt = 0; rt < 2; ++rt)
        a[rt] = *(const bf8v*)(A + (size_t)(n0 + rt * 16 + lr) * 256 + kt + lk * 8);
#pragma unroll
      for (int ct = 0; ct < 2; ++ct)
        bb[ct] = *(const bf8v*)(V + (size_t)(d0 + ct * 16 + lr) * 256 + kt + lk * 8);
#pragma unroll
      for (int rt = 0; rt < 2; ++rt)
#pragma unroll
        for (int ct = 0; ct < 2; ++ct)
          acc[t][rt][ct] = __builtin_amdgcn_mfma_f32_16x16x32_bf16(a[rt], bb[ct], acc[t][rt][ct], 0, 0, 0);
    }
  }
  // LIF over t (exact int dynamics) + router gate -> bits (bit t*4+r)
  unsigned sb2[2][2] = {{0, 0}, {0, 0}};
#pragma unroll
  for (int rt = 0; rt < 2; ++rt)
#pragma unroll
    for (int ct = 0; ct < 2; ++ct)
#pragma unroll
      for (int r = 0; r < 4; ++r) {
        int nl = rt * 16 + lk * 4 + r;
        float mem = 0.0f;
#pragma unroll
        for (int t = 0; t < 4; ++t) {
          float v = acc[t][rt][ct][r];
          mem += (v - mem) * 0.5f;
          if (mem >= 1.0f) {
            mem = 0.0f;
            if (wlds[(e * 4 + t) * 32 + nl]) sb2[rt][ct] |= 1u << (t * 4 + r);
          }
        }
      }
  // per-t: each wave deposits its expert's 0/1, readers sum 4 and write YT
  for (int t = 0; t < 4; ++t) {
    __syncthreads();
#pragma unroll
    for (int rt = 0; rt < 2; ++rt)
#pragma unroll
      for (int ct = 0; ct < 2; ++ct)
#pragma unroll
        for (int r = 0; r < 4; ++r) {
          int nl = rt * 16 + lk * 4 + r;
          int dl = ct * 16 + lr;
          wt[e][nl][dl] = ((sb2[rt][ct] >> (t * 4 + r)) & 1) ? (half_t)1.0f : (half_t)0.0f;
        }
    __syncthreads();
    int row = tid >> 3, cb = (tid & 7) * 4;
    h4v o4;
#pragma unroll
    for (int j = 0; j < 4; ++j) {
      float s = (float)wt[0][row][cb + j] + (float)wt[1][row][cb + j]
              + (float)wt[2][row][cb + j] + (float)wt[3][row][cb + j];
      o4[j] = (half_t)s;
    }
    *(h4v*)(YT + ((size_t)((t * 8 + b) * 256) + n0 + row) * 384 + d0 + cb) = o4;
  }
}

// ---------------- depthwise 3x3 NHWC fp16 + BN + LIF + gate -> M fp16 K-major --------------
__global__ __launch_bounds__(256) void dwconv_nhwc(
    const half_t* __restrict__ H, const float* __restrict__ DWT,
    const float* __restrict__ aS, const float* __restrict__ aB, half_t* __restrict__ M)
{
  int u = blockIdx.x * 256 + threadIdx.x;   // 8 * 256 * 1024
  int ch = u & 1023;
  int n = (u >> 10) & 255;
  int b = u >> 18;
  int px = n & 15, py = n >> 4;
  float w[9];
#pragma unroll
  for (int i = 0; i < 9; ++i) w[i] = DWT[i * HH + ch];
  float s = aS[ch], bb = aB[ch];
  float mem = 0.0f;
#pragma unroll
  for (int t = 0; t < 4; ++t) {
    size_t base = (size_t)(t * 8 + b) * 256;
    float acc = 0.0f;
#pragma unroll
    for (int dy = 0; dy < 3; ++dy) {
      int yy = py + dy - 1;
      if (yy < 0 || yy > 15) continue;
#pragma unroll
      for (int dx = 0; dx < 3; ++dx) {
        int xx = px + dx - 1;
        if (xx < 0 || xx > 15) continue;
        acc += (float)H[(base + yy * 16 + xx) * HID + ch] * w[dy * 3 + dx];
      }
    }
    float z = acc * s + bb;
    mem += (z - mem) * 0.5f;
    float sp = (mem >= 1.0f) ? 1.0f : 0.0f;
    mem = (sp != 0.0f) ? 0.0f : mem;
    float x2 = (float)H[(base + n) * HID + HH + ch];
    M[(base + n) * HH + ch] = (half_t)(sp * x2);
  }
}

} // namespace

extern "C" void kernel_launch(void* const* d_in, const int* in_sizes, int n_in,
                              void* d_out, int out_size, void* d_ws, size_t ws_size,
                              hipStream_t stream)
{
  const float* x         = (const float*)d_in[0];
  const float* k_w       = (const float*)d_in[2];
  const float* v_w       = (const float*)d_in[3];
  const float* router_w  = (const float*)d_in[4];
  const float* router_b  = (const float*)d_in[5];
  const float* router_g  = (const float*)d_in[6];
  const float* router_be = (const float*)d_in[7];
  const float* exp_w     = (const float*)d_in[8];
  const float* exp_g     = (const float*)d_in[9];
  const float* exp_b     = (const float*)d_in[10];
  const float* proj_w    = (const float*)d_in[11];
  const float* proj_b    = (const float*)d_in[12];
  const float* proj_g    = (const float*)d_in[13];
  const float* proj_be   = (const float*)d_in[14];
  const float* fc1_w     = (const float*)d_in[15];
  const float* fc1_b     = (const float*)d_in[16];
  const float* fc1_g     = (const float*)d_in[17];
  const float* fc1_be    = (const float*)d_in[18];
  const float* dw_w      = (const float*)d_in[19];
  const float* dw_b      = (const float*)d_in[20];
  const float* dw_g      = (const float*)d_in[21];
  const float* dw_be     = (const float*)d_in[22];
  const float* fc2_w     = (const float*)d_in[23];
  const float* fc2_b     = (const float*)d_in[24];
  const float* fc2_g     = (const float*)d_in[25];
  const float* fc2_be    = (const float*)d_in[26];

  float* ws  = (float*)d_ws;
  float* out = (float*)d_out;
  ushort_t* spkb = (ushort_t*)(ws + O_SPKB);
  ushort_t* qt   = (ushort_t*)(ws + O_QT);
  ushort_t* ktb  = (ushort_t*)(ws + O_KT);
  ushort_t* attb = (ushort_t*)(ws + O_ATTNB);
  half_t* wpre0 = (half_t*)(ws + O_WPRE0), *wpre1 = (half_t*)(ws + O_WPRE1);
  half_t* wprj0 = (half_t*)(ws + O_WPRJ0), *wprj1 = (half_t*)(ws + O_WPRJ1);
  half_t* wf10  = (half_t*)(ws + O_WF10),  *wf11  = (half_t*)(ws + O_WF11);
  half_t* wf20  = (half_t*)(ws + O_WF20),  *wf21  = (half_t*)(ws + O_WF21);
  half_t* xtpre0 = (half_t*)(ws + O_XTPRE), *xtpre1 = xtpre0 + (size_t)TB * N * C;
  half_t* yt    = (half_t*)(ws + O_YT);
  half_t* xf0   = (half_t*)(ws + O_XF0), *xf1 = (half_t*)(ws + O_XF1);
  half_t* hbuf  = (half_t*)(ws + O_H);
  half_t* mbuf  = (half_t*)(ws + O_M);
  dim3 blk(256);

  // setup: 2 launches
  affines_all<<<55, blk, 0, stream>>>(router_b, router_g, router_be, exp_g, exp_b,
                                      proj_g, proj_b, proj_be, fc1_g, fc1_b, fc1_be,
                                      dw_g, dw_b, dw_be, fc2_g, fc2_b, fc2_be, dw_w, ws);
  split_all<<<6528, blk, 0, stream>>>(k_w, v_w, router_w, exp_w, proj_w, fc1_w, fc2_w, ws);

  // pre projections: split(x) -> LDS-staged sgemm+LIF -> spkb (bf16 spikes)
  split_xt<<<dim3(8, 12, 32), blk, 0, stream>>>(x, xtpre0, xtpre1, C);
  sgemm_lif<3, 0><<<dim3(8, 14, 8), blk, 0, stream>>>(
      xtpre0, xtpre1, wpre0, wpre1, ws + O_A1S, ws + O_A1B, nullptr, spkb,
      nullptr, nullptr, 868, C);

  // attn path (exact bf16 MFMA)
  transpose_spk<<<dim3(8, 3, 32),  blk, 0, stream>>>(spkb, ktb, 0);
  transpose_spk<<<dim3(8, 3, 128), blk, 0, stream>>>(spkb, qt, 484);
  attn_mfma<<<dim3(2, 128), blk, 0, stream>>>(qt, ktb, attb);
  // fused res GEMM + RES-LIF + router sum -> YT fp16 (XCD-local batches)
  res_y<<<dim3(768), blk, 0, stream>>>(attb, spkb, yt);

  // proj: YT fp16 exact -> sgemm+LIF -> out = x + spike, also emits xf0/xf1 split
  sgemm_lif<2, 1><<<dim3(8, 6, 8), blk, 0, stream>>>(
      yt, nullptr, wprj0, wprj1, ws + O_APS, ws + O_APB, x, out, xf0, xf1, 384, C);

  // fc1: xf (from proj epilogue) -> sgemm+LIF -> H fp16 NHWC spikes
  sgemm_lif<3, 2><<<dim3(8, 32, 8), blk, 0, stream>>>(
      xf0, xf1, wf10, wf11, ws + O_AHS, ws + O_AHB, nullptr, hbuf,
      nullptr, nullptr, 2048, C);

  // depthwise conv + BN + LIF + gate -> M fp16 (binary, K-major)
  dwconv_nhwc<<<dim3(8192), blk, 0, stream>>>(hbuf, ws + O_DWT, ws + O_ADS, ws + O_ADB, mbuf);

  // fc2: M fp16 exact binary -> sgemm+LIF -> out += spike
  sgemm_lif<2, 3><<<dim3(8, 6, 8), blk, 0, stream>>>(
      mbuf, nullptr, wf20, wf21, ws + O_AFS, ws + O_AFB, nullptr, out,
      nullptr, nullptr, 384, HH);
}